// Round 3
// baseline (139.219 us; speedup 1.0000x reference)
//
#include <hip/hip_runtime.h>
#include <hip/hip_bf16.h>
#include <stdint.h>
#include <math.h>

// ---------- types ----------
typedef __bf16 bf16;
typedef bf16  bf16x4  __attribute__((ext_vector_type(4)));
typedef bf16  bf16x8  __attribute__((ext_vector_type(8)));
typedef float floatx4 __attribute__((ext_vector_type(4)));

#define MFMA_16x16x32_BF16(a, b, c) \
  __builtin_amdgcn_mfma_f32_16x16x32_bf16((a), (b), (c), 0, 0, 0)

// async global->LDS, 16B per lane. LDS dest is wave-uniform base + lane*16.
__device__ __forceinline__ void load_lds16(const void* g, void* l) {
  __builtin_amdgcn_global_load_lds(
      (const __attribute__((address_space(1))) unsigned int*)g,
      (__attribute__((address_space(3))) unsigned int*)l, 16, 0, 0);
}

// ---------- constants ----------
// B=2, L=2048, D=1024, H=16, dh=64, WINDOW=256
#define LSEQ 2048
#define DMODEL 1024
#define NH 16
#define DH 64

// ============================================================
// 1) merged pack: blocks 0..4095 -> hidden fp32->bf16;
//    blocks 4096..7167 -> W^T bf16 transpose (32x32 tiles, z=q/k/v)
// ============================================================
__global__ void pack_all(const float4* __restrict__ x, uint16_t* __restrict__ y,
                         const float* __restrict__ Wq, const float* __restrict__ Wk,
                         const float* __restrict__ Wv, uint16_t* __restrict__ Wt) {
  const int bi = blockIdx.x;
  if (bi < 4096) {
    int i = bi * 256 + threadIdx.x;
    float4 f = x[i];
    bf16x4 v;
    v[0] = (bf16)f.x; v[1] = (bf16)f.y; v[2] = (bf16)f.z; v[3] = (bf16)f.w;
    *(bf16x4*)&y[(size_t)i * 4] = v;
    return;
  }
  __shared__ float tile[32][33];
  const int p = bi - 4096;              // 0..3071
  const int z = p >> 10;                // /1024
  const int rem = p & 1023;
  const int k0 = (rem >> 5) * 32, n0 = (rem & 31) * 32;
  const float* W = (z == 0) ? Wq : (z == 1) ? Wk : Wv;
  const int tx = threadIdx.x & 31, ty = threadIdx.x >> 5;  // 32x8
#pragma unroll
  for (int i = 0; i < 4; ++i)
    tile[ty + i * 8][tx] = W[(size_t)(k0 + ty + i * 8) * DMODEL + n0 + tx];
  __syncthreads();
  uint16_t* out = Wt + (size_t)z * DMODEL * DMODEL;
#pragma unroll
  for (int i = 0; i < 4; ++i)
    *(bf16*)&out[(size_t)(n0 + ty + i * 8) * DMODEL + k0 + tx] =
        (bf16)tile[tx][ty + i * 8];
}

// ============================================================
// 3) QKV GEMM — 256x256 tile, 8-phase schedule (T3+T4+T5).
//    512 threads = 8 waves (2M x 4N), wave tile 128x64, BK=64,
//    2 K-tile LDS buffers (128 KB, 1 block/CU).
//    Per K-tile: 4 phases of 16 MFMA, barrier-paired; tile T+1 staged
//    during phases 1-2 of iter T; ONE counted vmcnt(4) per iter (never 0
//    in main loop except the final iteration); raw s_barrier.
//    Grid 192 = 16m x 4n x 3z, m pinned to XCD.
//    z=0 -> q*0.125 [B,H,L,dh]; z=1 -> k; z=2 -> v TRANSPOSED [B,H,dh,L]
//    with keys permuted within each aligned 32-key panel:
//    kk -> ((kk>>2)&3)*8 + ((kk>>4)&1)*4 + (kk&3)  (attn PV A-frag = 1 b128).
// ============================================================
__global__ __launch_bounds__(512, 2) void qkv_gemm8(
    const uint16_t* __restrict__ A, const uint16_t* __restrict__ Wt,
    const float* __restrict__ bq, const float* __restrict__ bk,
    const float* __restrict__ bv,
    uint16_t* __restrict__ outq, uint16_t* __restrict__ outk,
    uint16_t* __restrict__ outvt) {
  // buffer b (64KB) at b*32768 u16: A tile [256][64] at 0, B tile at 16384.
  __shared__ __attribute__((aligned(16))) uint16_t lds[65536];  // 128 KB

  const int xcd = blockIdx.x & 7;
  const int i = blockIdx.x >> 3;        // 0..23
  const int m0 = (xcd * 2 + (i & 1)) * 256;
  const int nz = i >> 1;                // 0..11
  const int n0 = (nz & 3) * 256;
  const int z = nz >> 2;
  const uint16_t* Bt = Wt + (size_t)z * DMODEL * DMODEL;
  const float* bias = (z == 0) ? bq : (z == 1) ? bk : bv;

  const int t = threadIdx.x;
  const int lane = t & 63;
  const int w = t >> 6;                 // 0..7
  const int wm = (w >> 2) * 128;        // 2 M-halves
  const int wn = (w & 3) * 64;          // 4 N-quarters
  const int col = lane & 15;
  const int quad = lane >> 4;

  floatx4 acc[8][4] = {};

  // stage part (0=A rows m0+, 1=B rows n0+) of K-tile kt into buffer bi.
  // 256 rows x 8 chunks of 16B; LDS dest linear, XOR swizzle on the
  // GLOBAL k-chunk (both-sides involution): slot sl holds chunk sl^(row&7).
  // 4 global_load_lds per wave per call.
  auto stage = [&](int kt, int bi, int part) {
    const int k0 = kt * 64;
    uint16_t* base = &lds[bi * 32768 + part * 16384];
    const uint16_t* src = part ? (Bt + (size_t)n0 * DMODEL)
                               : (A  + (size_t)m0 * DMODEL);
#pragma unroll
    for (int c = 0; c < 4; ++c) {
      int chunk = t + c * 512;          // 0..2047
      int row = chunk >> 3, sl = chunk & 7;
      const uint16_t* g = src + (size_t)row * DMODEL + k0 + ((sl ^ (row & 7)) * 8);
      load_lds16(g, &base[chunk * 8]);
    }
  };

  // prologue: tile 0 fully staged, drained.
  stage(0, 0, 0);
  stage(0, 0, 1);
  asm volatile("s_waitcnt vmcnt(0)" ::: "memory");
  __builtin_amdgcn_s_barrier();

  bf16x8 af[8];
  for (int kt = 0; kt < 16; ++kt) {
    const uint16_t* buf = &lds[(kt & 1) * 32768];
    const int nbi = (kt + 1) & 1;

    // ---- phase 1: A(k0) 8 reads + B(n01,k0) 2 reads, 16 MFMA ----
    if (kt < 15) {
      stage(kt + 1, nbi, 0);                   // +4 vmem
      // oldest 8 (all of tile kt) done; the 4 just issued may be in flight
      asm volatile("s_waitcnt vmcnt(4)" ::: "memory");
    } else {
      asm volatile("s_waitcnt vmcnt(0)" ::: "memory");
    }
    __builtin_amdgcn_s_barrier();
    __builtin_amdgcn_sched_barrier(0);  // don't hoist ds_reads above barrier
#pragma unroll
    for (int mi = 0; mi < 8; ++mi) {
      int r = wm + mi * 16 + col;
      af[mi] = *(const bf16x8*)&buf[r * 64 + ((quad ^ (r & 7)) * 8)];
    }
    {
      bf16x8 b0, b1;
      {
        int r = wn + col;
        b0 = *(const bf16x8*)&buf[16384 + r * 64 + ((quad ^ (r & 7)) * 8)];
        int r1 = wn + 16 + col;
        b1 = *(const bf16x8*)&buf[16384 + r1 * 64 + ((quad ^ (r1 & 7)) * 8)];
      }
      __builtin_amdgcn_s_setprio(1);
#pragma unroll
      for (int mi = 0; mi < 8; ++mi) {
        acc[mi][0] = MFMA_16x16x32_BF16(af[mi], b0, acc[mi][0]);
        acc[mi][1] = MFMA_16x16x32_BF16(af[mi], b1, acc[mi][1]);
      }
      __builtin_amdgcn_s_setprio(0);
    }
    __builtin_amdgcn_s_barrier();

    // ---- phase 2: B(n23,k0) 2 reads, 16 MFMA (reuse af) ----
    if (kt < 15) stage(kt + 1, nbi, 1);        // +4 vmem
    __builtin_amdgcn_s_barrier();
    {
      bf16x8 b2, b3;
      {
        int r = wn + 32 + col;
        b2 = *(const bf16x8*)&buf[16384 + r * 64 + ((quad ^ (r & 7)) * 8)];
        int r1 = wn + 48 + col;
        b3 = *(const bf16x8*)&buf[16384 + r1 * 64 + ((quad ^ (r1 & 7)) * 8)];
      }
      __builtin_amdgcn_s_setprio(1);
#pragma unroll
      for (int mi = 0; mi < 8; ++mi) {
        acc[mi][2] = MFMA_16x16x32_BF16(af[mi], b2, acc[mi][2]);
        acc[mi][3] = MFMA_16x16x32_BF16(af[mi], b3, acc[mi][3]);
      }
      __builtin_amdgcn_s_setprio(0);
    }
    __builtin_amdgcn_s_barrier();

    // ---- phase 3: A(k1) 8 reads + B(n01,k1) 2 reads, 16 MFMA ----
    __builtin_amdgcn_s_barrier();
#pragma unroll
    for (int mi = 0; mi < 8; ++mi) {
      int r = wm + mi * 16 + col;
      af[mi] = *(const bf16x8*)&buf[r * 64 + (((4 + quad) ^ (r & 7)) * 8)];
    }
    {
      bf16x8 b0, b1;
      {
        int r = wn + col;
        b0 = *(const bf16x8*)&buf[16384 + r * 64 + (((4 + quad) ^ (r & 7)) * 8)];
        int r1 = wn + 16 + col;
        b1 = *(const bf16x8*)&buf[16384 + r1 * 64 + (((4 + quad) ^ (r1 & 7)) * 8)];
      }
      __builtin_amdgcn_s_setprio(1);
#pragma unroll
      for (int mi = 0; mi < 8; ++mi) {
        acc[mi][0] = MFMA_16x16x32_BF16(af[mi], b0, acc[mi][0]);
        acc[mi][1] = MFMA_16x16x32_BF16(af[mi], b1, acc[mi][1]);
      }
      __builtin_amdgcn_s_setprio(0);
    }
    __builtin_amdgcn_s_barrier();

    // ---- phase 4: B(n23,k1) 2 reads, 16 MFMA ----
    __builtin_amdgcn_s_barrier();
    {
      bf16x8 b2, b3;
      {
        int r = wn + 32 + col;
        b2 = *(const bf16x8*)&buf[16384 + r * 64 + (((4 + quad) ^ (r & 7)) * 8)];
        int r1 = wn + 48 + col;
        b3 = *(const bf16x8*)&buf[16384 + r1 * 64 + (((4 + quad) ^ (r1 & 7)) * 8)];
      }
      __builtin_amdgcn_s_setprio(1);
#pragma unroll
      for (int mi = 0; mi < 8; ++mi) {
        acc[mi][2] = MFMA_16x16x32_BF16(af[mi], b2, acc[mi][2]);
        acc[mi][3] = MFMA_16x16x32_BF16(af[mi], b3, acc[mi][3]);
      }
      __builtin_amdgcn_s_setprio(0);
    }
    __builtin_amdgcn_s_barrier();
  }
  // nothing in flight here (final iter drained vmcnt(0)); barrier before
  // LDS reuse in the V^T epilogue.
  __builtin_amdgcn_s_barrier();

  // epilogue: C/D layout col=lane&15 (n), row=quad*4+reg (m)
  if (z != 2) {
    const float scale = (z == 0) ? 0.125f : 1.0f;  // fold 1/sqrt(dh) into q
    uint16_t* outp = (z == 0) ? outq : outk;
#pragma unroll
    for (int nj = 0; nj < 4; ++nj) {
      int gn = n0 + wn + nj * 16 + col;
      float bb = bias[gn];
      int h = gn >> 6, d = gn & 63;
#pragma unroll
      for (int mi = 0; mi < 8; ++mi) {
#pragma unroll
        for (int r = 0; r < 4; ++r) {
          int gm = m0 + wm + mi * 16 + quad * 4 + r;
          int b = gm >> 11, l = gm & 2047;
          *(bf16*)&outp[(((size_t)b * NH + h) * LSEQ + l) * DH + d] =
              (bf16)((acc[mi][nj][r] + bb) * scale);
        }
      }
    }
  } else {
    // V^T: transpose C through LDS (stride 136, 32-key-panel perm baked in),
    // two m-halves of 128 (buffer = 256n x 136 u16 = 68 KB, fits 128 KB).
    const int b = m0 >> 11;
#pragma unroll
    for (int H = 0; H < 2; ++H) {
      if (wm == H * 128) {
#pragma unroll
        for (int nj = 0; nj < 4; ++nj) {
          int n = wn + nj * 16 + col;
          float bb = bias[n0 + n];
#pragma unroll
          for (int mi = 0; mi < 8; ++mi) {
            int mb = mi * 16 + quad * 4;       // local m within half, 0..124
            int pp = (mb & ~31) | (((mb >> 2) & 3) << 3) | (((mb >> 4) & 1) << 2);
#pragma unroll
            for (int r = 0; r < 4; ++r)
              *(bf16*)&lds[n * 136 + pp + r] = (bf16)(acc[mi][nj][r] + bb);
          }
        }
      }
      __syncthreads();
      // coalesced store: 512 threads, n = t>>1 (0..255), mh = (t&1)*64
      {
        const int n = t >> 1, mh = (t & 1) * 64;
        const int gn = n0 + n, d = gn & 63, h = gn >> 6;
        const int l0 = (m0 & 2047) + H * 128 + mh;
        uint16_t* dst = &outvt[(((size_t)b * NH + h) * DH + d) * LSEQ + l0];
        const uint16_t* src = &lds[n * 136 + mh];
#pragma unroll
        for (int j = 0; j < 8; ++j)
          *(bf16x8*)&dst[j * 8] = *(const bf16x8*)&src[j * 8];
      }
      __syncthreads();
    }
  }
}

// ============================================================
// 4) windowed attention, block-cooperative LDS staging, 64-KEY CHUNKS.
//    K tile 64x64, V^T tile 64d x 64keys (two permuted 32-key panels),
//    both double-buffered (32 KB LDS, 4 blocks/CU). setprio around MFMA
//    clusters (T5 — independent blocks at different phases).
// ============================================================
__global__ __launch_bounds__(256, 4) void attn(
    const uint16_t* __restrict__ Q, const uint16_t* __restrict__ K,
    const uint16_t* __restrict__ Vt, float* __restrict__ out) {
  __shared__ __attribute__((aligned(16))) uint16_t kbuf[2][4096];  // 64 keys x 64 d
  __shared__ __attribute__((aligned(16))) uint16_t vbuf[2][4096];  // 64 d x 64 keys

  const int t = threadIdx.x;
  const int lane = t & 63;
  const int w = t >> 6;
  const int xcd = blockIdx.x & 7;
  const int slot = blockIdx.x >> 3;          // 0..127
  const int bh = xcd * 4 + (slot >> 5);      // 4 heads per XCD
  const int q0 = (slot & 31) * 64;           // block's query base
  const int q0w = q0 + w * 16;               // this wave's 16 queries
  const int b = bh >> 4, h = bh & 15;
  const uint16_t* Qp = Q + (size_t)bh * LSEQ * DH;
  const uint16_t* Kp = K + (size_t)bh * LSEQ * DH;
  const uint16_t* Vp = Vt + (size_t)bh * DH * LSEQ;
  const int col = lane & 15, quad = lane >> 4;

  bf16x8 qf0 = *(const bf16x8*)&Qp[(size_t)(q0w + col) * DH + quad * 8];
  bf16x8 qf1 = *(const bf16x8*)&Qp[(size_t)(q0w + col) * DH + 32 + quad * 8];

  bf16x8 ones;
#pragma unroll
  for (int u = 0; u < 8; ++u) ones[u] = (bf16)1.0f;

  // chunk c covers keys [q0-256+64c, +64); skip fully-negative chunks.
  const int c_start = (q0 < 256) ? ((256 - q0) >> 6) : 0;

  floatx4 o[4] = {};                    // O^T: d=nj*16+quad*4+r, q=col
  floatx4 lac = {0.f, 0.f, 0.f, 0.f};   // row sums (all regs equal l[q=col])

  auto stage = [&](int c, int bi) {
    const int kc = q0 - 256 + 64 * c;   // >= 0 by construction
    int ci = w * 64 + lane;
    {
      int row = ci >> 3, s = ci & 7;    // rows 0..31
      const uint16_t* g = Kp + (size_t)(kc + row) * DH + ((s ^ (row & 7)) * 8);
      load_lds16(g, &kbuf[bi][w * 512]);
      int row2 = row + 32;              // rows 32..63
      const uint16_t* g2 = Kp + (size_t)(kc + row2) * DH + ((s ^ (row2 & 7)) * 8);
      load_lds16(g2, &kbuf[bi][2048 + w * 512]);
    }
    {
      int d = ci >> 3, s = ci & 7;      // d 0..31
      const uint16_t* g = Vp + (size_t)d * LSEQ + kc + ((s ^ (d & 7)) * 8);
      load_lds16(g, &vbuf[bi][w * 512]);
      int d2 = d + 32;                  // d 32..63
      const uint16_t* g2 = Vp + (size_t)d2 * LSEQ + kc + ((s ^ (d2 & 7)) * 8);
      load_lds16(g2, &vbuf[bi][2048 + w * 512]);
    }
  };

  stage(c_start, c_start & 1);

  for (int c = c_start; c <= 4; ++c) {
    __syncthreads();                    // drains vmcnt: buf[c&1] ready
    if (c < 4) stage(c + 1, (c + 1) & 1);

    const int kc = q0 - 256 + 64 * c;
    const int hi = q0w + 15, lo = q0w - 255;
    if (kc <= hi && kc + 64 > lo) {     // chunk intersects this wave's window
      const uint16_t* kb_ = kbuf[c & 1];
      const uint16_t* vb_ = vbuf[c & 1];

      // S^T = K . Q^T : A = K rows (m=key), B = Q (n=query); 4 key-subtiles
      floatx4 sT[4] = {{0,0,0,0},{0,0,0,0},{0,0,0,0},{0,0,0,0}};
      __builtin_amdgcn_s_setprio(1);
#pragma unroll
      for (int sub = 0; sub < 4; ++sub) {
        int r_ = sub * 16 + col;        // key row in 64-row tile
        bf16x8 ka  = *(const bf16x8*)&kb_[r_ * 64 + ((quad ^ (r_ & 7)) * 8)];
        bf16x8 kb2 = *(const bf16x8*)&kb_[r_ * 64 + (((4 + quad) ^ (r_ & 7)) * 8)];
        sT[sub] = MFMA_16x16x32_BF16(ka, qf0, sT[sub]);
        sT[sub] = MFMA_16x16x32_BF16(kb2, qf1, sT[sub]);
      }
      __builtin_amdgcn_s_setprio(0);

      // per-query band mask + exp; pack two P^T B-frags (one per 32-key panel)
      // panel-local mapping: key(quad,j) = (j>>2)*16 + quad*4 + (j&3).
      const bool needm = (kc < q0w - 240) | (kc + 63 > q0w);
      const int q = q0w + col;
      bf16x8 pb[2];
#pragma unroll
      for (int sel = 0; sel < 2; ++sel) {
#pragma unroll
        for (int sp = 0; sp < 2; ++sp) {
#pragma unroll
          for (int r = 0; r < 4; ++r) {
            float v = sT[sel * 2 + sp][r];
            if (needm) {
              int key = kc + sel * 32 + sp * 16 + quad * 4 + r;
              v = ((key <= q) & (key > q - 256)) ? v : -INFINITY;  // exp(-inf)=0
            }
            pb[sel][sp * 4 + r] = (bf16)__expf(v);
          }
        }
      }

      // O^T += V^T . P^T — one b128 A-frag per (nj, panel)
      __builtin_amdgcn_s_setprio(1);
#pragma unroll
      for (int nj = 0; nj < 4; ++nj) {
        int d = nj * 16 + col;
        bf16x8 va0 = *(const bf16x8*)&vb_[d * 64 + ((quad ^ (d & 7)) * 8)];
        bf16x8 va1 = *(const bf16x8*)&vb_[d * 64 + (((4 + quad) ^ (d & 7)) * 8)];
        o[nj] = MFMA_16x16x32_BF16(va0, pb[0], o[nj]);
        o[nj] = MFMA_16x16x32_BF16(va1, pb[1], o[nj]);
      }
      lac = MFMA_16x16x32_BF16(ones, pb[0], lac);
      lac = MFMA_16x16x32_BF16(ones, pb[1], lac);
      __builtin_amdgcn_s_setprio(0);
    }
  }

  float rinv = 1.0f / lac[0];           // all lac regs equal l[q=col]
#pragma unroll
  for (int nj = 0; nj < 4; ++nj) {
    float4 v4;
    v4.x = o[nj][0] * rinv; v4.y = o[nj][1] * rinv;
    v4.z = o[nj][2] * rinv; v4.w = o[nj][3] * rinv;
    *(float4*)&out[((size_t)b * LSEQ + q0w + col) * DMODEL + h * DH + nj * 16 + quad * 4] = v4;
  }
}

// ============================================================
// launch
// ============================================================
extern "C" void kernel_launch(void* const* d_in, const int* in_sizes, int n_in,
                              void* d_out, int out_size, void* d_ws, size_t ws_size,
                              hipStream_t stream) {
  const float* hidden = (const float*)d_in[0];
  const float* Wq = (const float*)d_in[1];
  const float* bq = (const float*)d_in[2];
  const float* Wk = (const float*)d_in[3];
  const float* bk = (const float*)d_in[4];
  const float* Wv = (const float*)d_in[5];
  const float* bv = (const float*)d_in[6];
  float* out = (float*)d_out;

  // workspace layout (bytes): needs 38 MB
  char* ws = (char*)d_ws;
  uint16_t* hb  = (uint16_t*)(ws);                       // 8 MB  bf16 hidden
  uint16_t* Wt  = (uint16_t*)(ws + ((size_t)8  << 20));  // 6 MB  bf16 W^T x3
  uint16_t* qb  = (uint16_t*)(ws + ((size_t)14 << 20));  // 8 MB  q*0.125 [B,H,L,dh]
  uint16_t* kb  = (uint16_t*)(ws + ((size_t)22 << 20));  // 8 MB  k [B,H,L,dh]
  uint16_t* vtb = (uint16_t*)(ws + ((size_t)30 << 20));  // 8 MB  v^T perm [B,H,dh,L]

  pack_all<<<7168, 256, 0, stream>>>((const float4*)hidden, hb, Wq, Wk, Wv, Wt);
  qkv_gemm8<<<192, 512, 0, stream>>>(hb, Wt, bq, bk, bv, qb, kb, vtb);
  attn<<<1024, 256, 0, stream>>>(qb, kb, vtb, out);
}

// Round 4
// 135.453 us; speedup vs baseline: 1.0278x; 1.0278x over previous
//
#include <hip/hip_runtime.h>
#include <hip/hip_bf16.h>
#include <stdint.h>
#include <math.h>

// ---------- types ----------
typedef __bf16 bf16;
typedef bf16  bf16x4  __attribute__((ext_vector_type(4)));
typedef bf16  bf16x8  __attribute__((ext_vector_type(8)));
typedef float floatx4 __attribute__((ext_vector_type(4)));

#define MFMA_16x16x32_BF16(a, b, c) \
  __builtin_amdgcn_mfma_f32_16x16x32_bf16((a), (b), (c), 0, 0, 0)

// async global->LDS, 16B per lane. LDS dest is wave-uniform base + lane*16.
__device__ __forceinline__ void load_lds16(const void* g, void* l) {
  __builtin_amdgcn_global_load_lds(
      (const __attribute__((address_space(1))) unsigned int*)g,
      (__attribute__((address_space(3))) unsigned int*)l, 16, 0, 0);
}

// ---------- constants ----------
// B=2, L=2048, D=1024, H=16, dh=64, WINDOW=256
#define LSEQ 2048
#define DMODEL 1024
#define NH 16
#define DH 64

// ============================================================
// 1) merged pack: blocks 0..4095 -> hidden fp32->bf16;
//    blocks 4096..7167 -> W^T bf16 transpose (32x32 tiles, z=q/k/v)
// ============================================================
__global__ void pack_all(const float4* __restrict__ x, uint16_t* __restrict__ y,
                         const float* __restrict__ Wq, const float* __restrict__ Wk,
                         const float* __restrict__ Wv, uint16_t* __restrict__ Wt) {
  const int bi = blockIdx.x;
  if (bi < 4096) {
    int i = bi * 256 + threadIdx.x;
    float4 f = x[i];
    bf16x4 v;
    v[0] = (bf16)f.x; v[1] = (bf16)f.y; v[2] = (bf16)f.z; v[3] = (bf16)f.w;
    *(bf16x4*)&y[(size_t)i * 4] = v;
    return;
  }
  __shared__ float tile[32][33];
  const int p = bi - 4096;              // 0..3071
  const int z = p >> 10;                // /1024
  const int rem = p & 1023;
  const int k0 = (rem >> 5) * 32, n0 = (rem & 31) * 32;
  const float* W = (z == 0) ? Wq : (z == 1) ? Wk : Wv;
  const int tx = threadIdx.x & 31, ty = threadIdx.x >> 5;  // 32x8
#pragma unroll
  for (int i = 0; i < 4; ++i)
    tile[ty + i * 8][tx] = W[(size_t)(k0 + ty + i * 8) * DMODEL + n0 + tx];
  __syncthreads();
  uint16_t* out = Wt + (size_t)z * DMODEL * DMODEL;
#pragma unroll
  for (int i = 0; i < 4; ++i)
    *(bf16*)&out[(size_t)(n0 + ty + i * 8) * DMODEL + k0 + tx] =
        (bf16)tile[tx][ty + i * 8];
}

// ============================================================
// 3) QKV GEMM — 256x256 tile, BK=64, ONE barrier per K-tile.
//    512 threads = 8 waves (2M x 4N), wave tile 128x64, 2 K-tile LDS
//    buffers (128 KB, 1 block/CU).
//    Schedule per iter: vmcnt(0) [free: tile kt's loads issued a full
//    body (~2500cy) ago] -> s_barrier [tile kt visible to all; all waves
//    done reading buf[nbi]] -> stage(kt+1 -> buf[nbi]) [8 async loads,
//    in flight across the whole body] -> 24 ds_read + 64 MFMA free-flow.
//    No intra-tile barriers: waves drift, so one wave's LDS reads overlap
//    another's MFMAs (the round-3 lockstep burst serialization is gone).
//    Grid 192 = 16m x 4n x 3z, m pinned to XCD.
//    z=0 -> q*0.125 [B,H,L,dh]; z=1 -> k; z=2 -> v TRANSPOSED [B,H,dh,L]
//    with keys permuted within each aligned 32-key panel:
//    kk -> ((kk>>2)&3)*8 + ((kk>>4)&1)*4 + (kk&3)  (attn PV A-frag = 1 b128).
// ============================================================
__global__ __launch_bounds__(512, 2) void qkv_gemm8(
    const uint16_t* __restrict__ A, const uint16_t* __restrict__ Wt,
    const float* __restrict__ bq, const float* __restrict__ bk,
    const float* __restrict__ bv,
    uint16_t* __restrict__ outq, uint16_t* __restrict__ outk,
    uint16_t* __restrict__ outvt) {
  // buffer b (64KB) at b*32768 u16: A tile [256][64] at 0, B tile at 16384.
  __shared__ __attribute__((aligned(16))) uint16_t lds[65536];  // 128 KB

  const int xcd = blockIdx.x & 7;
  const int i = blockIdx.x >> 3;        // 0..23
  const int m0 = (xcd * 2 + (i & 1)) * 256;
  const int nz = i >> 1;                // 0..11
  const int n0 = (nz & 3) * 256;
  const int z = nz >> 2;
  const uint16_t* Bt = Wt + (size_t)z * DMODEL * DMODEL;
  const float* bias = (z == 0) ? bq : (z == 1) ? bk : bv;

  const int t = threadIdx.x;
  const int lane = t & 63;
  const int w = t >> 6;                 // 0..7
  const int wm = (w >> 2) * 128;        // 2 M-halves
  const int wn = (w & 3) * 64;          // 4 N-quarters
  const int col = lane & 15;
  const int quad = lane >> 4;

  floatx4 acc[8][4] = {};

  // stage part (0=A rows m0+, 1=B rows n0+) of K-tile kt into buffer bi.
  // 256 rows x 8 chunks of 16B; LDS dest linear, XOR swizzle on the
  // GLOBAL k-chunk (both-sides involution): slot sl holds chunk sl^(row&7).
  auto stage = [&](int kt, int bi, int part) {
    const int k0 = kt * 64;
    uint16_t* base = &lds[bi * 32768 + part * 16384];
    const uint16_t* src = part ? (Bt + (size_t)n0 * DMODEL)
                               : (A  + (size_t)m0 * DMODEL);
#pragma unroll
    for (int c = 0; c < 4; ++c) {
      int chunk = t + c * 512;          // 0..2047
      int row = chunk >> 3, sl = chunk & 7;
      const uint16_t* g = src + (size_t)row * DMODEL + k0 + ((sl ^ (row & 7)) * 8);
      load_lds16(g, &base[chunk * 8]);
    }
  };

  // prologue: tile 0's 8 loads issued; waited at iter 0's vmcnt.
  stage(0, 0, 0);
  stage(0, 0, 1);

  for (int kt = 0; kt < 16; ++kt) {
    const uint16_t* buf = &lds[(kt & 1) * 32768];
    const int nbi = (kt + 1) & 1;

    // tile kt's 8 loads done (issued one full body ago -> wait is ~free).
    asm volatile("s_waitcnt vmcnt(0)" ::: "memory");
    // all waves: tile kt visible AND everyone is done reading buf[nbi].
    __builtin_amdgcn_s_barrier();
    __builtin_amdgcn_sched_barrier(0);  // nothing moves above the barrier
    if (kt < 15) {                      // overwrite of buf[nbi] now safe
      stage(kt + 1, nbi, 0);
      stage(kt + 1, nbi, 1);
    }
    __builtin_amdgcn_sched_barrier(0);  // stage issue stays ahead of reads

    bf16x8 af[8], b0, b1, b2, b3;
    // ---- k-half 0: 12 ds_read_b128, 32 MFMA ----
#pragma unroll
    for (int mi = 0; mi < 8; ++mi) {
      int r = wm + mi * 16 + col;
      af[mi] = *(const bf16x8*)&buf[r * 64 + ((quad ^ (r & 7)) * 8)];
    }
    {
      int r0 = wn + col, r1 = wn + 16 + col, r2 = wn + 32 + col, r3 = wn + 48 + col;
      b0 = *(const bf16x8*)&buf[16384 + r0 * 64 + ((quad ^ (r0 & 7)) * 8)];
      b1 = *(const bf16x8*)&buf[16384 + r1 * 64 + ((quad ^ (r1 & 7)) * 8)];
      b2 = *(const bf16x8*)&buf[16384 + r2 * 64 + ((quad ^ (r2 & 7)) * 8)];
      b3 = *(const bf16x8*)&buf[16384 + r3 * 64 + ((quad ^ (r3 & 7)) * 8)];
    }
    __builtin_amdgcn_s_setprio(1);
#pragma unroll
    for (int mi = 0; mi < 8; ++mi) {
      acc[mi][0] = MFMA_16x16x32_BF16(af[mi], b0, acc[mi][0]);
      acc[mi][1] = MFMA_16x16x32_BF16(af[mi], b1, acc[mi][1]);
      acc[mi][2] = MFMA_16x16x32_BF16(af[mi], b2, acc[mi][2]);
      acc[mi][3] = MFMA_16x16x32_BF16(af[mi], b3, acc[mi][3]);
    }
    __builtin_amdgcn_s_setprio(0);

    // ---- k-half 1: 12 ds_read_b128, 32 MFMA ----
#pragma unroll
    for (int mi = 0; mi < 8; ++mi) {
      int r = wm + mi * 16 + col;
      af[mi] = *(const bf16x8*)&buf[r * 64 + (((4 + quad) ^ (r & 7)) * 8)];
    }
    {
      int r0 = wn + col, r1 = wn + 16 + col, r2 = wn + 32 + col, r3 = wn + 48 + col;
      b0 = *(const bf16x8*)&buf[16384 + r0 * 64 + (((4 + quad) ^ (r0 & 7)) * 8)];
      b1 = *(const bf16x8*)&buf[16384 + r1 * 64 + (((4 + quad) ^ (r1 & 7)) * 8)];
      b2 = *(const bf16x8*)&buf[16384 + r2 * 64 + (((4 + quad) ^ (r2 & 7)) * 8)];
      b3 = *(const bf16x8*)&buf[16384 + r3 * 64 + (((4 + quad) ^ (r3 & 7)) * 8)];
    }
    __builtin_amdgcn_s_setprio(1);
#pragma unroll
    for (int mi = 0; mi < 8; ++mi) {
      acc[mi][0] = MFMA_16x16x32_BF16(af[mi], b0, acc[mi][0]);
      acc[mi][1] = MFMA_16x16x32_BF16(af[mi], b1, acc[mi][1]);
      acc[mi][2] = MFMA_16x16x32_BF16(af[mi], b2, acc[mi][2]);
      acc[mi][3] = MFMA_16x16x32_BF16(af[mi], b3, acc[mi][3]);
    }
    __builtin_amdgcn_s_setprio(0);
  }
  // all waves done with buffers before LDS reuse in the V^T epilogue.
  __builtin_amdgcn_s_barrier();

  // epilogue: C/D layout col=lane&15 (n), row=quad*4+reg (m)
  if (z != 2) {
    const float scale = (z == 0) ? 0.125f : 1.0f;  // fold 1/sqrt(dh) into q
    uint16_t* outp = (z == 0) ? outq : outk;
#pragma unroll
    for (int nj = 0; nj < 4; ++nj) {
      int gn = n0 + wn + nj * 16 + col;
      float bb = bias[gn];
      int h = gn >> 6, d = gn & 63;
#pragma unroll
      for (int mi = 0; mi < 8; ++mi) {
#pragma unroll
        for (int r = 0; r < 4; ++r) {
          int gm = m0 + wm + mi * 16 + quad * 4 + r;
          int b = gm >> 11, l = gm & 2047;
          *(bf16*)&outp[(((size_t)b * NH + h) * LSEQ + l) * DH + d] =
              (bf16)((acc[mi][nj][r] + bb) * scale);
        }
      }
    }
  } else {
    // V^T: transpose C through LDS (stride 136, 32-key-panel perm baked in),
    // two m-halves of 128 (buffer = 256n x 136 u16 = 68 KB, fits 128 KB).
    const int b = m0 >> 11;
#pragma unroll
    for (int H = 0; H < 2; ++H) {
      if (wm == H * 128) {
#pragma unroll
        for (int nj = 0; nj < 4; ++nj) {
          int n = wn + nj * 16 + col;
          float bb = bias[n0 + n];
#pragma unroll
          for (int mi = 0; mi < 8; ++mi) {
            int mb = mi * 16 + quad * 4;       // local m within half, 0..124
            int pp = (mb & ~31) | (((mb >> 2) & 3) << 3) | (((mb >> 4) & 1) << 2);
#pragma unroll
            for (int r = 0; r < 4; ++r)
              *(bf16*)&lds[n * 136 + pp + r] = (bf16)(acc[mi][nj][r] + bb);
          }
        }
      }
      __syncthreads();
      // coalesced store: 512 threads, n = t>>1 (0..255), mh = (t&1)*64
      {
        const int n = t >> 1, mh = (t & 1) * 64;
        const int gn = n0 + n, d = gn & 63, h = gn >> 6;
        const int l0 = (m0 & 2047) + H * 128 + mh;
        uint16_t* dst = &outvt[(((size_t)b * NH + h) * DH + d) * LSEQ + l0];
        const uint16_t* src = &lds[n * 136 + mh];
#pragma unroll
        for (int j = 0; j < 8; ++j)
          *(bf16x8*)&dst[j * 8] = *(const bf16x8*)&src[j * 8];
      }
      __syncthreads();
    }
  }
}

// ============================================================
// 4) windowed attention, block-cooperative LDS staging, 64-KEY CHUNKS.
//    K tile 64x64, V^T tile 64d x 64keys (two permuted 32-key panels),
//    both double-buffered (32 KB LDS, 4 blocks/CU). setprio around MFMA
//    clusters (T5 — independent blocks at different phases).
// ============================================================
__global__ __launch_bounds__(256, 4) void attn(
    const uint16_t* __restrict__ Q, const uint16_t* __restrict__ K,
    const uint16_t* __restrict__ Vt, float* __restrict__ out) {
  __shared__ __attribute__((aligned(16))) uint16_t kbuf[2][4096];  // 64 keys x 64 d
  __shared__ __attribute__((aligned(16))) uint16_t vbuf[2][4096];  // 64 d x 64 keys

  const int t = threadIdx.x;
  const int lane = t & 63;
  const int w = t >> 6;
  const int xcd = blockIdx.x & 7;
  const int slot = blockIdx.x >> 3;          // 0..127
  const int bh = xcd * 4 + (slot >> 5);      // 4 heads per XCD
  const int q0 = (slot & 31) * 64;           // block's query base
  const int q0w = q0 + w * 16;               // this wave's 16 queries
  const int b = bh >> 4, h = bh & 15;
  const uint16_t* Qp = Q + (size_t)bh * LSEQ * DH;
  const uint16_t* Kp = K + (size_t)bh * LSEQ * DH;
  const uint16_t* Vp = Vt + (size_t)bh * DH * LSEQ;
  const int col = lane & 15, quad = lane >> 4;

  bf16x8 qf0 = *(const bf16x8*)&Qp[(size_t)(q0w + col) * DH + quad * 8];
  bf16x8 qf1 = *(const bf16x8*)&Qp[(size_t)(q0w + col) * DH + 32 + quad * 8];

  bf16x8 ones;
#pragma unroll
  for (int u = 0; u < 8; ++u) ones[u] = (bf16)1.0f;

  // chunk c covers keys [q0-256+64c, +64); skip fully-negative chunks.
  const int c_start = (q0 < 256) ? ((256 - q0) >> 6) : 0;

  floatx4 o[4] = {};                    // O^T: d=nj*16+quad*4+r, q=col
  floatx4 lac = {0.f, 0.f, 0.f, 0.f};   // row sums (all regs equal l[q=col])

  auto stage = [&](int c, int bi) {
    const int kc = q0 - 256 + 64 * c;   // >= 0 by construction
    int ci = w * 64 + lane;
    {
      int row = ci >> 3, s = ci & 7;    // rows 0..31
      const uint16_t* g = Kp + (size_t)(kc + row) * DH + ((s ^ (row & 7)) * 8);
      load_lds16(g, &kbuf[bi][w * 512]);
      int row2 = row + 32;              // rows 32..63
      const uint16_t* g2 = Kp + (size_t)(kc + row2) * DH + ((s ^ (row2 & 7)) * 8);
      load_lds16(g2, &kbuf[bi][2048 + w * 512]);
    }
    {
      int d = ci >> 3, s = ci & 7;      // d 0..31
      const uint16_t* g = Vp + (size_t)d * LSEQ + kc + ((s ^ (d & 7)) * 8);
      load_lds16(g, &vbuf[bi][w * 512]);
      int d2 = d + 32;                  // d 32..63
      const uint16_t* g2 = Vp + (size_t)d2 * LSEQ + kc + ((s ^ (d2 & 7)) * 8);
      load_lds16(g2, &vbuf[bi][2048 + w * 512]);
    }
  };

  stage(c_start, c_start & 1);

  for (int c = c_start; c <= 4; ++c) {
    __syncthreads();                    // drains vmcnt: buf[c&1] ready
    if (c < 4) stage(c + 1, (c + 1) & 1);

    const int kc = q0 - 256 + 64 * c;
    const int hi = q0w + 15, lo = q0w - 255;
    if (kc <= hi && kc + 64 > lo) {     // chunk intersects this wave's window
      const uint16_t* kb_ = kbuf[c & 1];
      const uint16_t* vb_ = vbuf[c & 1];

      // S^T = K . Q^T : A = K rows (m=key), B = Q (n=query); 4 key-subtiles
      floatx4 sT[4] = {{0,0,0,0},{0,0,0,0},{0,0,0,0},{0,0,0,0}};
      __builtin_amdgcn_s_setprio(1);
#pragma unroll
      for (int sub = 0; sub < 4; ++sub) {
        int r_ = sub * 16 + col;        // key row in 64-row tile
        bf16x8 ka  = *(const bf16x8*)&kb_[r_ * 64 + ((quad ^ (r_ & 7)) * 8)];
        bf16x8 kb2 = *(const bf16x8*)&kb_[r_ * 64 + (((4 + quad) ^ (r_ & 7)) * 8)];
        sT[sub] = MFMA_16x16x32_BF16(ka, qf0, sT[sub]);
        sT[sub] = MFMA_16x16x32_BF16(kb2, qf1, sT[sub]);
      }
      __builtin_amdgcn_s_setprio(0);

      // per-query band mask + exp; pack two P^T B-frags (one per 32-key panel)
      // panel-local mapping: key(quad,j) = (j>>2)*16 + quad*4 + (j&3).
      const bool needm = (kc < q0w - 240) | (kc + 63 > q0w);
      const int q = q0w + col;
      bf16x8 pb[2];
#pragma unroll
      for (int sel = 0; sel < 2; ++sel) {
#pragma unroll
        for (int sp = 0; sp < 2; ++sp) {
#pragma unroll
          for (int r = 0; r < 4; ++r) {
            float v = sT[sel * 2 + sp][r];
            if (needm) {
              int key = kc + sel * 32 + sp * 16 + quad * 4 + r;
              v = ((key <= q) & (key > q - 256)) ? v : -INFINITY;  // exp(-inf)=0
            }
            pb[sel][sp * 4 + r] = (bf16)__expf(v);
          }
        }
      }

      // O^T += V^T . P^T — one b128 A-frag per (nj, panel)
      __builtin_amdgcn_s_setprio(1);
#pragma unroll
      for (int nj = 0; nj < 4; ++nj) {
        int d = nj * 16 + col;
        bf16x8 va0 = *(const bf16x8*)&vb_[d * 64 + ((quad ^ (d & 7)) * 8)];
        bf16x8 va1 = *(const bf16x8*)&vb_[d * 64 + (((4 + quad) ^ (d & 7)) * 8)];
        o[nj] = MFMA_16x16x32_BF16(va0, pb[0], o[nj]);
        o[nj] = MFMA_16x16x32_BF16(va1, pb[1], o[nj]);
      }
      lac = MFMA_16x16x32_BF16(ones, pb[0], lac);
      lac = MFMA_16x16x32_BF16(ones, pb[1], lac);
      __builtin_amdgcn_s_setprio(0);
    }
  }

  float rinv = 1.0f / lac[0];           // all lac regs equal l[q=col]
#pragma unroll
  for (int nj = 0; nj < 4; ++nj) {
    float4 v4;
    v4.x = o[nj][0] * rinv; v4.y = o[nj][1] * rinv;
    v4.z = o[nj][2] * rinv; v4.w = o[nj][3] * rinv;
    *(float4*)&out[((size_t)b * LSEQ + q0w + col) * DMODEL + h * DH + nj * 16 + quad * 4] = v4;
  }
}

// ============================================================
// launch
// ============================================================
extern "C" void kernel_launch(void* const* d_in, const int* in_sizes, int n_in,
                              void* d_out, int out_size, void* d_ws, size_t ws_size,
                              hipStream_t stream) {
  const float* hidden = (const float*)d_in[0];
  const float* Wq = (const float*)d_in[1];
  const float* bq = (const float*)d_in[2];
  const float* Wk = (const float*)d_in[3];
  const float* bk = (const float*)d_in[4];
  const float* Wv = (const float*)d_in[5];
  const float* bv = (const float*)d_in[6];
  float* out = (float*)d_out;

  // workspace layout (bytes): needs 38 MB
  char* ws = (char*)d_ws;
  uint16_t* hb  = (uint16_t*)(ws);                       // 8 MB  bf16 hidden
  uint16_t* Wt  = (uint16_t*)(ws + ((size_t)8  << 20));  // 6 MB  bf16 W^T x3
  uint16_t* qb  = (uint16_t*)(ws + ((size_t)14 << 20));  // 8 MB  q*0.125 [B,H,L,dh]
  uint16_t* kb  = (uint16_t*)(ws + ((size_t)22 << 20));  // 8 MB  k [B,H,L,dh]
  uint16_t* vtb = (uint16_t*)(ws + ((size_t)30 << 20));  // 8 MB  v^T perm [B,H,dh,L]

  pack_all<<<7168, 256, 0, stream>>>((const float4*)hidden, hb, Wq, Wk, Wv, Wt);
  qkv_gemm8<<<192, 512, 0, stream>>>(hb, Wt, bq, bk, bv, qb, kb, vtb);
  attn<<<1024, 256, 0, stream>>>(qb, kb, vtb, out);
}

// Round 5
// 127.434 us; speedup vs baseline: 1.0925x; 1.0629x over previous
//
#include <hip/hip_runtime.h>
#include <hip/hip_bf16.h>
#include <stdint.h>
#include <math.h>

// ---------- types ----------
typedef __bf16 bf16;
typedef bf16  bf16x4  __attribute__((ext_vector_type(4)));
typedef bf16  bf16x8  __attribute__((ext_vector_type(8)));
typedef float floatx4 __attribute__((ext_vector_type(4)));

#define MFMA_16x16x32_BF16(a, b, c) \
  __builtin_amdgcn_mfma_f32_16x16x32_bf16((a), (b), (c), 0, 0, 0)

// async global->LDS, 16B per lane. LDS dest is wave-uniform base + lane*16.
__device__ __forceinline__ void load_lds16(const void* g, void* l) {
  __builtin_amdgcn_global_load_lds(
      (const __attribute__((address_space(1))) unsigned int*)g,
      (__attribute__((address_space(3))) unsigned int*)l, 16, 0, 0);
}

// ---------- constants ----------
// B=2, L=2048, D=1024, H=16, dh=64, WINDOW=256
#define LSEQ 2048
#define DMODEL 1024
#define NH 16
#define DH 64

// ============================================================
// 1) merged pack: blocks 0..4095 -> hidden fp32->bf16;
//    blocks 4096..7167 -> W^T bf16 transpose (32x32 tiles, z=q/k/v)
// ============================================================
__global__ void pack_all(const float4* __restrict__ x, uint16_t* __restrict__ y,
                         const float* __restrict__ Wq, const float* __restrict__ Wk,
                         const float* __restrict__ Wv, uint16_t* __restrict__ Wt) {
  const int bi = blockIdx.x;
  if (bi < 4096) {
    int i = bi * 256 + threadIdx.x;
    float4 f = x[i];
    bf16x4 v;
    v[0] = (bf16)f.x; v[1] = (bf16)f.y; v[2] = (bf16)f.z; v[3] = (bf16)f.w;
    *(bf16x4*)&y[(size_t)i * 4] = v;
    return;
  }
  __shared__ float tile[32][33];
  const int p = bi - 4096;              // 0..3071
  const int z = p >> 10;                // /1024
  const int rem = p & 1023;
  const int k0 = (rem >> 5) * 32, n0 = (rem & 31) * 32;
  const float* W = (z == 0) ? Wq : (z == 1) ? Wk : Wv;
  const int tx = threadIdx.x & 31, ty = threadIdx.x >> 5;  // 32x8
#pragma unroll
  for (int i = 0; i < 4; ++i)
    tile[ty + i * 8][tx] = W[(size_t)(k0 + ty + i * 8) * DMODEL + n0 + tx];
  __syncthreads();
  uint16_t* out = Wt + (size_t)z * DMODEL * DMODEL;
#pragma unroll
  for (int i = 0; i < 4; ++i)
    *(bf16*)&out[(size_t)(n0 + ty + i * 8) * DMODEL + k0 + tx] =
        (bf16)tile[tx][ty + i * 8];
}

// ============================================================
// 3) QKV GEMM — 128x192 tiles over the FUSED 4096x3072 output.
//    Grid 512 (all 256 CUs, 2 blocks/CU), 256 threads = 4 waves,
//    wave tile 64x96 (acc[4][6]), BK=64, dbuf LDS = 80 KB (2/CU exact).
//    All 20 frag ds_reads issue up-front (fits 256-reg cap at 2 w/SIMD)
//    -> compiler's fine lgkmcnt pipelines reads under MFMAs; two
//    independent blocks/CU desync read-bursts vs MFMA-bursts.
//    One barrier + vmcnt(0) per K-tile (loads issued one body earlier).
//    Columns span z: per 16-col group, z = gcol>>10 picks out/bias/scale.
//    V is written PLAIN [B,H,L,dh] (transpose moved to vtrans).
// ============================================================
__global__ __launch_bounds__(256, 2) void qkv_gemm(
    const uint16_t* __restrict__ A, const uint16_t* __restrict__ Wt,
    const float* __restrict__ bq, const float* __restrict__ bk,
    const float* __restrict__ bv,
    uint16_t* __restrict__ outq, uint16_t* __restrict__ outk,
    uint16_t* __restrict__ outv) {
  // buffer b at b*20480 u16: A tile [128][64] at 0, B tile [192][64] at 8192.
  __shared__ __attribute__((aligned(16))) uint16_t lds[40960];  // 80 KB

  const int xcd = blockIdx.x & 7;
  const int i = blockIdx.x >> 3;        // 0..63
  const int m0 = (xcd * 4 + (i & 3)) * 128;   // XCD owns 4 panels (1MB A in L2)
  const int n0 = (i >> 2) * 192;        // 0..2880 in fused 3072-col space

  const int t = threadIdx.x;
  const int lane = t & 63;
  const int w = t >> 6;                 // 0..3
  const int wm = (w >> 1) * 64;
  const int wn = (w & 1) * 96;
  const int col = lane & 15;
  const int quad = lane >> 4;

  floatx4 acc[4][6] = {};

  // stage K-tile kt into buffer bi: A 1024 + B 1536 16B-chunks, 10/thread.
  // LDS dest linear; XOR swizzle on the GLOBAL k-chunk (involution):
  // slot sl of row r holds k-chunk sl^(r&7).
  auto stage = [&](int kt, int bi) {
    const int k0 = kt * 64;
    uint16_t* base = &lds[bi * 20480];
#pragma unroll
    for (int c = 0; c < 10; ++c) {
      int chunk = t + c * 256;          // 0..2559
      if (chunk < 1024) {               // A rows 0..127
        int row = chunk >> 3, sl = chunk & 7;
        const uint16_t* g =
            A + (size_t)(m0 + row) * DMODEL + k0 + ((sl ^ (row & 7)) * 8);
        load_lds16(g, &base[chunk * 8]);
      } else {                          // B rows 0..191 (z-split per row)
        int cb = chunk - 1024;
        int row = cb >> 3, sl = cb & 7;
        int gc = n0 + row;              // fused col 0..3071
        const uint16_t* g = Wt + ((size_t)(gc >> 10) << 20) +
                            (size_t)(gc & 1023) * DMODEL + k0 +
                            ((sl ^ (row & 7)) * 8);
        load_lds16(g, &base[8192 + cb * 8]);
      }
    }
  };

  stage(0, 0);
  for (int kt = 0; kt < 16; ++kt) {
    const uint16_t* buf = &lds[(kt & 1) * 20480];

    // tile kt's 10 loads done (issued one full body ago -> wait ~free).
    asm volatile("s_waitcnt vmcnt(0)" ::: "memory");
    __builtin_amdgcn_s_barrier();       // kt visible; buf[nbi] free
    __builtin_amdgcn_sched_barrier(0);
    if (kt < 15) stage(kt + 1, (kt + 1) & 1);
    __builtin_amdgcn_sched_barrier(0);

    // all 20 frag reads up-front; compiler's lgkmcnt pipelines MFMAs under
    // the later reads. khalf0 = k-chunks quad, khalf1 = 4+quad.
    bf16x8 a0[4], b0[6], a1[4], b1[6];
#pragma unroll
    for (int mi = 0; mi < 4; ++mi) {
      int r = wm + mi * 16 + col;
      a0[mi] = *(const bf16x8*)&buf[r * 64 + ((quad ^ (r & 7)) * 8)];
    }
#pragma unroll
    for (int nj = 0; nj < 6; ++nj) {
      int r = wn + nj * 16 + col;
      b0[nj] = *(const bf16x8*)&buf[8192 + r * 64 + ((quad ^ (r & 7)) * 8)];
    }
#pragma unroll
    for (int mi = 0; mi < 4; ++mi) {
      int r = wm + mi * 16 + col;
      a1[mi] = *(const bf16x8*)&buf[r * 64 + (((4 + quad) ^ (r & 7)) * 8)];
    }
#pragma unroll
    for (int nj = 0; nj < 6; ++nj) {
      int r = wn + nj * 16 + col;
      b1[nj] = *(const bf16x8*)&buf[8192 + r * 64 + (((4 + quad) ^ (r & 7)) * 8)];
    }

    __builtin_amdgcn_s_setprio(1);
#pragma unroll
    for (int mi = 0; mi < 4; ++mi)
#pragma unroll
      for (int nj = 0; nj < 6; ++nj)
        acc[mi][nj] = MFMA_16x16x32_BF16(a0[mi], b0[nj], acc[mi][nj]);
    __builtin_amdgcn_s_setprio(0);
    __builtin_amdgcn_s_setprio(1);
#pragma unroll
    for (int mi = 0; mi < 4; ++mi)
#pragma unroll
      for (int nj = 0; nj < 6; ++nj)
        acc[mi][nj] = MFMA_16x16x32_BF16(a1[mi], b1[nj], acc[mi][nj]);
    __builtin_amdgcn_s_setprio(0);
  }

  // epilogue: C/D layout col=lane&15 (n), row=quad*4+reg (m); z per 16-col
  // group (1024 % 16 == 0 -> uniform within group).
#pragma unroll
  for (int nj = 0; nj < 6; ++nj) {
    int gc = n0 + wn + nj * 16 + col;   // fused col
    int zz = gc >> 10, rem = gc & 1023;
    const float* biasp = (zz == 0) ? bq : (zz == 1) ? bk : bv;
    uint16_t* outp = (zz == 0) ? outq : (zz == 1) ? outk : outv;
    const float scale = (zz == 0) ? 0.125f : 1.0f;
    float bb = biasp[rem];
    int h = rem >> 6, d = rem & 63;
#pragma unroll
    for (int mi = 0; mi < 4; ++mi) {
#pragma unroll
      for (int r = 0; r < 4; ++r) {
        int gm = m0 + wm + mi * 16 + quad * 4 + r;
        int b = gm >> 11, l = gm & 2047;
        *(bf16*)&outp[(((size_t)b * NH + h) * LSEQ + l) * DH + d] =
            (bf16)((acc[mi][nj][r] + bb) * scale);
      }
    }
  }
}

// ============================================================
// 3b) V transpose: [B,H,L,dh] -> [B,H,dh,L] with the 32-key-panel
//     permutation attn expects: within each aligned 32-key panel,
//     key kk stored at (kk&~31)|((kk>>2)&3)<<3|((kk>>4)&1)<<2|(kk&3).
//     64x64 tiles through LDS, coalesced b128 both sides. ~16 MB total.
// ============================================================
__global__ __launch_bounds__(256) void vtrans(const uint16_t* __restrict__ V,
                                              uint16_t* __restrict__ Vt) {
  __shared__ uint16_t tl[64 * 68];      // row d, stride 68 (pad 4)
  const int t = threadIdx.x;
  const int bh = blockIdx.x >> 5;       // 0..31
  const int l0 = (blockIdx.x & 31) * 64;
  const uint16_t* src = V + ((size_t)bh * LSEQ + l0) * DH;

  const int l = t >> 2, dc = (t & 3) * 16;   // 16 d-values per thread
  bf16x8 v0 = *(const bf16x8*)&src[(size_t)l * DH + dc];
  bf16x8 v1 = *(const bf16x8*)&src[(size_t)l * DH + dc + 8];
  const int pp = (l & 32) | (((l >> 2) & 3) << 3) | (((l >> 4) & 1) << 2) | (l & 3);
#pragma unroll
  for (int j = 0; j < 8; ++j) {
    tl[(dc + j) * 68 + pp]     = ((const uint16_t*)&v0)[j];
    tl[(dc + 8 + j) * 68 + pp] = ((const uint16_t*)&v1)[j];
  }
  __syncthreads();
  const int d = t >> 2, lc = (t & 3) * 16;
  uint16_t* dst = Vt + ((size_t)bh * DH + d) * LSEQ + l0 + lc;
  *(bf16x8*)&dst[0] = *(const bf16x8*)&tl[d * 68 + lc];
  *(bf16x8*)&dst[8] = *(const bf16x8*)&tl[d * 68 + lc + 8];
}

// ============================================================
// 4) windowed attention, block-cooperative LDS staging, 64-KEY CHUNKS.
//    K tile 64x64, V^T tile 64d x 64keys (two permuted 32-key panels),
//    both double-buffered (32 KB LDS, 4 blocks/CU). setprio around MFMA
//    clusters (T5 — independent blocks at different phases).
// ============================================================
__global__ __launch_bounds__(256, 4) void attn(
    const uint16_t* __restrict__ Q, const uint16_t* __restrict__ K,
    const uint16_t* __restrict__ Vt, float* __restrict__ out) {
  __shared__ __attribute__((aligned(16))) uint16_t kbuf[2][4096];  // 64 keys x 64 d
  __shared__ __attribute__((aligned(16))) uint16_t vbuf[2][4096];  // 64 d x 64 keys

  const int t = threadIdx.x;
  const int lane = t & 63;
  const int w = t >> 6;
  const int xcd = blockIdx.x & 7;
  const int slot = blockIdx.x >> 3;          // 0..127
  const int bh = xcd * 4 + (slot >> 5);      // 4 heads per XCD
  const int q0 = (slot & 31) * 64;           // block's query base
  const int q0w = q0 + w * 16;               // this wave's 16 queries
  const int b = bh >> 4, h = bh & 15;
  const uint16_t* Qp = Q + (size_t)bh * LSEQ * DH;
  const uint16_t* Kp = K + (size_t)bh * LSEQ * DH;
  const uint16_t* Vp = Vt + (size_t)bh * DH * LSEQ;
  const int col = lane & 15, quad = lane >> 4;

  bf16x8 qf0 = *(const bf16x8*)&Qp[(size_t)(q0w + col) * DH + quad * 8];
  bf16x8 qf1 = *(const bf16x8*)&Qp[(size_t)(q0w + col) * DH + 32 + quad * 8];

  bf16x8 ones;
#pragma unroll
  for (int u = 0; u < 8; ++u) ones[u] = (bf16)1.0f;

  // chunk c covers keys [q0-256+64c, +64); skip fully-negative chunks.
  const int c_start = (q0 < 256) ? ((256 - q0) >> 6) : 0;

  floatx4 o[4] = {};                    // O^T: d=nj*16+quad*4+r, q=col
  floatx4 lac = {0.f, 0.f, 0.f, 0.f};   // row sums (all regs equal l[q=col])

  auto stage = [&](int c, int bi) {
    const int kc = q0 - 256 + 64 * c;   // >= 0 by construction
    int ci = w * 64 + lane;
    {
      int row = ci >> 3, s = ci & 7;    // rows 0..31
      const uint16_t* g = Kp + (size_t)(kc + row) * DH + ((s ^ (row & 7)) * 8);
      load_lds16(g, &kbuf[bi][w * 512]);
      int row2 = row + 32;              // rows 32..63
      const uint16_t* g2 = Kp + (size_t)(kc + row2) * DH + ((s ^ (row2 & 7)) * 8);
      load_lds16(g2, &kbuf[bi][2048 + w * 512]);
    }
    {
      int d = ci >> 3, s = ci & 7;      // d 0..31
      const uint16_t* g = Vp + (size_t)d * LSEQ + kc + ((s ^ (d & 7)) * 8);
      load_lds16(g, &vbuf[bi][w * 512]);
      int d2 = d + 32;                  // d 32..63
      const uint16_t* g2 = Vp + (size_t)d2 * LSEQ + kc + ((s ^ (d2 & 7)) * 8);
      load_lds16(g2, &vbuf[bi][2048 + w * 512]);
    }
  };

  stage(c_start, c_start & 1);

  for (int c = c_start; c <= 4; ++c) {
    __syncthreads();                    // drains vmcnt: buf[c&1] ready
    if (c < 4) stage(c + 1, (c + 1) & 1);

    const int kc = q0 - 256 + 64 * c;
    const int hi = q0w + 15, lo = q0w - 255;
    if (kc <= hi && kc + 64 > lo) {     // chunk intersects this wave's window
      const uint16_t* kb_ = kbuf[c & 1];
      const uint16_t* vb_ = vbuf[c & 1];

      // S^T = K . Q^T : A = K rows (m=key), B = Q (n=query); 4 key-subtiles
      floatx4 sT[4] = {{0,0,0,0},{0,0,0,0},{0,0,0,0},{0,0,0,0}};
      __builtin_amdgcn_s_setprio(1);
#pragma unroll
      for (int sub = 0; sub < 4; ++sub) {
        int r_ = sub * 16 + col;        // key row in 64-row tile
        bf16x8 ka  = *(const bf16x8*)&kb_[r_ * 64 + ((quad ^ (r_ & 7)) * 8)];
        bf16x8 kb2 = *(const bf16x8*)&kb_[r_ * 64 + (((4 + quad) ^ (r_ & 7)) * 8)];
        sT[sub] = MFMA_16x16x32_BF16(ka, qf0, sT[sub]);
        sT[sub] = MFMA_16x16x32_BF16(kb2, qf1, sT[sub]);
      }
      __builtin_amdgcn_s_setprio(0);

      // per-query band mask + exp; pack two P^T B-frags (one per 32-key panel)
      // panel-local mapping: key(quad,j) = (j>>2)*16 + quad*4 + (j&3).
      const bool needm = (kc < q0w - 240) | (kc + 63 > q0w);
      const int q = q0w + col;
      bf16x8 pb[2];
#pragma unroll
      for (int sel = 0; sel < 2; ++sel) {
#pragma unroll
        for (int sp = 0; sp < 2; ++sp) {
#pragma unroll
          for (int r = 0; r < 4; ++r) {
            float v = sT[sel * 2 + sp][r];
            if (needm) {
              int key = kc + sel * 32 + sp * 16 + quad * 4 + r;
              v = ((key <= q) & (key > q - 256)) ? v : -INFINITY;  // exp(-inf)=0
            }
            pb[sel][sp * 4 + r] = (bf16)__expf(v);
          }
        }
      }

      // O^T += V^T . P^T — one b128 A-frag per (nj, panel)
      __builtin_amdgcn_s_setprio(1);
#pragma unroll
      for (int nj = 0; nj < 4; ++nj) {
        int d = nj * 16 + col;
        bf16x8 va0 = *(const bf16x8*)&vb_[d * 64 + ((quad ^ (d & 7)) * 8)];
        bf16x8 va1 = *(const bf16x8*)&vb_[d * 64 + (((4 + quad) ^ (d & 7)) * 8)];
        o[nj] = MFMA_16x16x32_BF16(va0, pb[0], o[nj]);
        o[nj] = MFMA_16x16x32_BF16(va1, pb[1], o[nj]);
      }
      lac = MFMA_16x16x32_BF16(ones, pb[0], lac);
      lac = MFMA_16x16x32_BF16(ones, pb[1], lac);
      __builtin_amdgcn_s_setprio(0);
    }
  }

  float rinv = 1.0f / lac[0];           // all lac regs equal l[q=col]
#pragma unroll
  for (int nj = 0; nj < 4; ++nj) {
    float4 v4;
    v4.x = o[nj][0] * rinv; v4.y = o[nj][1] * rinv;
    v4.z = o[nj][2] * rinv; v4.w = o[nj][3] * rinv;
    *(float4*)&out[((size_t)b * LSEQ + q0w + col) * DMODEL + h * DH + nj * 16 + quad * 4] = v4;
  }
}

// ============================================================
// launch
// ============================================================
extern "C" void kernel_launch(void* const* d_in, const int* in_sizes, int n_in,
                              void* d_out, int out_size, void* d_ws, size_t ws_size,
                              hipStream_t stream) {
  const float* hidden = (const float*)d_in[0];
  const float* Wq = (const float*)d_in[1];
  const float* bq = (const float*)d_in[2];
  const float* Wk = (const float*)d_in[3];
  const float* bk = (const float*)d_in[4];
  const float* Wv = (const float*)d_in[5];
  const float* bv = (const float*)d_in[6];
  float* out = (float*)d_out;

  // workspace layout (bytes): needs 46 MB
  char* ws = (char*)d_ws;
  uint16_t* hb  = (uint16_t*)(ws);                       // 8 MB  bf16 hidden
  uint16_t* Wt  = (uint16_t*)(ws + ((size_t)8  << 20));  // 6 MB  bf16 W^T x3
  uint16_t* qb  = (uint16_t*)(ws + ((size_t)14 << 20));  // 8 MB  q*0.125 [B,H,L,dh]
  uint16_t* kb  = (uint16_t*)(ws + ((size_t)22 << 20));  // 8 MB  k [B,H,L,dh]
  uint16_t* vb  = (uint16_t*)(ws + ((size_t)30 << 20));  // 8 MB  v [B,H,L,dh]
  uint16_t* vtb = (uint16_t*)(ws + ((size_t)38 << 20));  // 8 MB  v^T perm [B,H,dh,L]

  pack_all<<<7168, 256, 0, stream>>>((const float4*)hidden, hb, Wq, Wk, Wv, Wt);
  qkv_gemm<<<512, 256, 0, stream>>>(hb, Wt, bq, bk, bv, qb, kb, vb);
  vtrans<<<1024, 256, 0, stream>>>(vb, vtb);
  attn<<<1024, 256, 0, stream>>>(qb, kb, vtb, out);
}